// Round 9
// baseline (13.999 us; speedup 1.0000x reference)
//
#include <hip/hip_runtime.h>

// Cochlea: per-f compress + first-order IIR (alpha=0.9) along T + ReLU.
// B=32, T=4096, F=64.
//
// Round-9: same algorithm/traffic as round 8 (512-row group per block,
// 64-row uniform warm-up => 1.125x read amp, register carry across tiles,
// XCD-aware placement, 2 blocks/CU), but finer phase granularity:
// tile = 128 rows (kL=8), WALK 4 tiles per block. Each tile stage is
// {scan (staged regs) -> barrier -> Horner -> prefetch tile k+2 -> store},
// so load and store streams interleave at 8-row granularity and per-CU
// phase troughs shrink. g==0 uses virtual carry = compressed[t=0].

typedef float vf2 __attribute__((ext_vector_type(2)));

namespace {
constexpr int kB     = 32;
constexpr int kT     = 4096;
constexpr int kF2    = 32;             // full row = 32 vf2 (256 B)
constexpr int kFH    = 16;             // vf2 lanes per F-half
constexpr int kL     = 8;              // rows per segment
constexpr int kSEG   = 16;             // segments per tile
constexpr int kTILE  = kSEG * kL;      // 128 rows per tile
constexpr int kWALK  = 4;              // tiles walked per block
constexpr int kGRP   = kWALK * kTILE;  // 512 rows per block
constexpr int kNG    = kT / kGRP;      // 8 groups per b
constexpr int kLW    = 4;              // warm rows per thread
constexpr int kWROWS = kSEG * kLW;     // 64 warm-up rows
constexpr float kA   = 0.9f;
constexpr float kOmA = 1.0f - kA;

constexpr float apow(int n) { float r = 1.f; for (int i = 0; i < n; ++i) r *= 0.9f; return r; }
constexpr float kA8 = apow(kL);        // alpha^8  (per-segment decay)
constexpr float kA4 = apow(kLW);       // alpha^4  (warm-carry decay)
}

__global__ __launch_bounds__(256, 2) void cochlea_kernel(
    const vf2* __restrict__ spec,
    const vf2* __restrict__ ftune,
    const float* __restrict__ thr_p,
    const float* __restrict__ ratio_p,
    vf2* __restrict__ out)
{
    const int tid = threadIdx.x;
    const int f2  = tid & (kFH - 1);
    const int seg = tid >> 4;                 // 0..15

    // XCD-aware decode: d%8 == b%8 -> all 16 blocks of b on one XCD L2.
    const int d    = blockIdx.x;
    const int blo  = d & 7;
    const int rest = d >> 3;                  // 0..63
    const int b    = ((rest >> 4) << 3) | blo;
    const int sub  = rest & 15;               // 0..15
    const int g    = sub >> 1;                // 0..7
    const int fh   = sub & 1;

    const float thr   = thr_p[0];
    const float ratio = ratio_p[0];
    const vf2 ft = ftune[fh * kFH + f2];

    const size_t rowbase = (size_t)b * kT * kF2 + fh * kFH + f2;
    const int tg0 = g * kGRP;
    const vf2* spBase = spec + rowbase;

    auto comp = [&](vf2 x) -> vf2 {
        float ta = x.x * ft.x, tc = x.y * ft.y;
        float ca = fmaf(ta - thr, ratio, thr);
        float cc = fmaf(tc - thr, ratio, thr);
        vf2 v;
        v.x = (ta > thr) ? ca : ta;
        v.y = (tc > thr) ? cc : tc;
        return v;
    };

    // ---- up-front loads: warm + tile0 + tile1 (all independent) ----
    vf2 wx[kLW];
    if (g > 0) {
        const vf2* wp = spBase + (size_t)(tg0 - kWROWS + seg * kLW) * kF2;
        #pragma unroll
        for (int j = 0; j < kLW; ++j) wx[j] = wp[(size_t)j * kF2];
    }
    vf2 xvA[kL], xvB[kL];
    {
        const vf2* sp0 = spBase + (size_t)(tg0 + 0 * kTILE + seg * kL) * kF2;
        #pragma unroll
        for (int j = 0; j < kL; ++j) xvA[j] = sp0[(size_t)j * kF2];
        const vf2* sp1 = spBase + (size_t)(tg0 + 1 * kTILE + seg * kL) * kF2;
        #pragma unroll
        for (int j = 0; j < kL; ++j) xvB[j] = sp1[(size_t)j * kF2];
    }

    // ---- warm-up scan (g>0): 4 rows per seg ----
    vf2 yw = {0.f, 0.f};
    if (g > 0) {
        #pragma unroll
        for (int j = 0; j < kLW; ++j) {
            vf2 v = comp(wx[j]);
            yw.x = fmaf(kA, yw.x, kOmA * v.x);
            yw.y = fmaf(kA, yw.y, kOmA * v.y);
        }
    }

    __shared__ vf2 lds_c[kWALK][kSEG][kFH];
    __shared__ vf2 lds_w[kSEG][kFH];
    __shared__ vf2 lds_v0[kFH];
    lds_w[seg][f2] = yw;

    vf2 I = {0.f, 0.f};                       // carry into current tile
    vf2 r[kL];

    #pragma unroll
    for (int k = 0; k < kWALK; ++k) {
        vf2* xv = (k & 1) ? xvB : xvA;        // k is unroll-constant

        // ---- scan tile k from staged regs (y0 = 0) ----
        vf2 y = {0.f, 0.f};
        #pragma unroll
        for (int j = 0; j < kL; ++j) {
            vf2 v = comp(xv[j]);
            if (k == 0 && j == 0 && seg == 0) lds_v0[f2] = v;
            y.x = fmaf(kA, y.x, kOmA * v.x);
            y.y = fmaf(kA, y.y, kOmA * v.y);
            r[j] = y;
        }
        lds_c[k][seg][f2] = y;
        __syncthreads();

        // ---- carry into tile 0: virtual (g==0) or warm A4-Horner ----
        if (k == 0) {
            if (g == 0) {
                I = lds_v0[f2];               // y_{-1} = c0 -> exact y0 = c0
            } else {
                I = {0.f, 0.f};
                #pragma unroll
                for (int j = 0; j < kSEG; ++j) {
                    vf2 w = lds_w[j][f2];
                    I.x = fmaf(kA4, I.x, w.x);
                    I.y = fmaf(kA4, I.y, w.y);
                }
            }
        }

        // ---- in-tile combine: capture own carry-in; final acc -> next I ----
        vf2 acc = I, yin = {0.f, 0.f};
        #pragma unroll
        for (int j = 0; j < kSEG; ++j) {
            if (j == seg) yin = acc;
            vf2 c = lds_c[k][j][f2];
            acc.x = fmaf(kA8, acc.x, c.x);
            acc.y = fmaf(kA8, acc.y, c.y);
        }
        I = acc;

        // ---- prefetch tile k+2 into the register bank just freed ----
        if (k + 2 < kWALK) {
            const vf2* spn = spBase + (size_t)(tg0 + (k + 2) * kTILE + seg * kL) * kF2;
            #pragma unroll
            for (int j = 0; j < kL; ++j) xv[j] = spn[(size_t)j * kF2];
        }

        // ---- fixup + store tile k ----
        vf2* op = out + rowbase + (size_t)(tg0 + k * kTILE + seg * kL) * kF2;
        float ap = kA;
        #pragma unroll
        for (int j = 0; j < kL; ++j) {
            vf2 o;
            o.x = fmaxf(fmaf(ap, yin.x, r[j].x), 0.f);
            o.y = fmaxf(fmaf(ap, yin.y, r[j].y), 0.f);
            __builtin_nontemporal_store(o, op + (size_t)j * kF2);
            ap *= kA;
        }
    }
}

extern "C" void kernel_launch(void* const* d_in, const int* in_sizes, int n_in,
                              void* d_out, int out_size, void* d_ws, size_t ws_size,
                              hipStream_t stream) {
    const vf2*   spec  = (const vf2*)d_in[0];
    const vf2*   ftune = (const vf2*)d_in[1];
    const float* thr   = (const float*)d_in[2];
    const float* ratio = (const float*)d_in[3];
    vf2* out = (vf2*)d_out;

    dim3 grid(kB * kNG * 2), block(kSEG * kFH);   // 512 blocks x 256 threads
    cochlea_kernel<<<grid, block, 0, stream>>>(spec, ftune, thr, ratio, out);
}

// Round 10
// 13.608 us; speedup vs baseline: 1.0288x; 1.0288x over previous
//
#include <hip/hip_runtime.h>

// Cochlea: per-f compress + first-order IIR (alpha=0.9) along T + ReLU.
// B=32, T=4096, F=64.
//
// FINAL (round-8 structure, best measured: 13.6 us; probes in both
// directions regressed: coarser phases 16.1 us, finer phases 14.0 us).
// Algorithm: walk-2 tiles per block with register carry (exact), 64-row
// uniform warm-up (alpha^64 ~ 1.2e-3 truncation, threshold 2.78e-2)
// -> read amplification 1.125x, warm re-reads L2-resident via XCD-aware
// placement. HBM traffic ~67 MB = algorithmic floor; 13.6 us = 78% of
// the 6.3 TB/s mixed-copy ceiling (10.6 us ideal) - remainder is DRAM
// ramp/turnaround on a ~13 us kernel.
//  - F split in halves: block = 256 thr (16 segs x 16 f2), grid = 512
//    = 2 blocks/CU -> one block's store burst overlaps the other's loads.
//  - ALL 36 loads (warm + tile0 + tile1) issued before any compute.
//  - XCD-aware block index: all 16 blocks of a given b land on XCD b%8,
//    so warm re-reads hit that XCD's L2 (1 MB input per b << 4 MB L2).
// g==0 carry-in = compressed[t=0] (virtual carry, exact y0 = c0).

typedef float vf2 __attribute__((ext_vector_type(2)));

namespace {
constexpr int kB    = 32;
constexpr int kT    = 4096;
constexpr int kF2   = 32;              // full row = 32 vf2 (256 B)
constexpr int kFH   = 16;              // vf2 lanes per F-half
constexpr int kL    = 16;              // rows per segment
constexpr int kSEG  = 16;              // segments per tile
constexpr int kTBLK = kSEG * kL;       // 256 rows per tile
constexpr int kGRP  = 2 * kTBLK;       // 512 rows per block (walk 2)
constexpr int kNG   = kT / kGRP;       // 8 groups per b
constexpr int kLW   = 4;               // warm rows per thread
constexpr int kWROWS = kSEG * kLW;     // 64 warm-up rows
constexpr float kA   = 0.9f;
constexpr float kOmA = 1.0f - kA;

constexpr float apow(int n) { float r = 1.f; for (int i = 0; i < n; ++i) r *= 0.9f; return r; }
constexpr float kA16 = apow(kL);       // alpha^16
constexpr float kA4  = apow(kLW);      // alpha^4
}

__global__ __launch_bounds__(256, 2) void cochlea_kernel(
    const vf2* __restrict__ spec,
    const vf2* __restrict__ ftune,
    const float* __restrict__ thr_p,
    const float* __restrict__ ratio_p,
    vf2* __restrict__ out)
{
    const int tid = threadIdx.x;
    const int f2  = tid & (kFH - 1);
    const int seg = tid >> 4;                 // 0..15

    // XCD-aware decode: d%8 == b%8 -> all groups of b share one XCD L2.
    const int d    = blockIdx.x;
    const int blo  = d & 7;
    const int rest = d >> 3;                  // 0..63
    const int b    = ((rest >> 4) << 3) | blo;
    const int sub  = rest & 15;               // 0..15
    const int g    = sub >> 1;                // 0..7
    const int fh   = sub & 1;

    const float thr   = thr_p[0];
    const float ratio = ratio_p[0];
    const vf2 ft = ftune[fh * kFH + f2];

    const size_t rowbase = (size_t)b * kT * kF2 + fh * kFH + f2;
    const int tg0 = g * kGRP;

    auto comp = [&](vf2 x) -> vf2 {
        float ta = x.x * ft.x, tc = x.y * ft.y;
        float ca = fmaf(ta - thr, ratio, thr);
        float cc = fmaf(tc - thr, ratio, thr);
        vf2 v;
        v.x = (ta > thr) ? ca : ta;
        v.y = (tc > thr) ? cc : tc;
        return v;
    };

    // ---- issue ALL loads up front (warm + tile0 + tile1) ----
    const vf2* sp0 = spec + rowbase + (size_t)(tg0 + seg * kL) * kF2;
    const vf2* sp1 = sp0 + (size_t)kTBLK * kF2;

    vf2 wx[kLW];
    if (g > 0) {
        const vf2* wp = spec + rowbase + (size_t)(tg0 - kWROWS + seg * kLW) * kF2;
        #pragma unroll
        for (int j = 0; j < kLW; ++j) wx[j] = wp[(size_t)j * kF2];
    }
    vf2 xv0[kL];
    #pragma unroll
    for (int j = 0; j < kL; ++j) xv0[j] = sp0[(size_t)j * kF2];
    vf2 xv1[kL];
    #pragma unroll
    for (int j = 0; j < kL; ++j) xv1[j] = sp1[(size_t)j * kF2];

    // ---- warm-up scan (g>0): 4 rows per seg ----
    vf2 yw = {0.f, 0.f};
    if (g > 0) {
        #pragma unroll
        for (int j = 0; j < kLW; ++j) {
            vf2 v = comp(wx[j]);
            yw.x = fmaf(kA, yw.x, kOmA * v.x);
            yw.y = fmaf(kA, yw.y, kOmA * v.y);
        }
    }

    // ---- tile 0 local scan (y0 = 0) ----
    vf2 r[kL];
    vf2 y  = {0.f, 0.f};
    vf2 v0 = {0.f, 0.f};
    #pragma unroll
    for (int j = 0; j < kL; ++j) {
        vf2 v = comp(xv0[j]);
        if (j == 0) v0 = v;
        y.x = fmaf(kA, y.x, kOmA * v.x);
        y.y = fmaf(kA, y.y, kOmA * v.y);
        r[j] = y;
    }

    __shared__ vf2 lds_c[2][kSEG][kFH];
    __shared__ vf2 lds_w[kSEG][kFH];
    __shared__ vf2 lds_v0[kFH];
    lds_c[0][seg][f2] = y;
    lds_w[seg][f2] = yw;
    if (seg == 0) lds_v0[f2] = v0;
    __syncthreads();

    // ---- Hw = carry into tile 0 ----
    vf2 Hw;
    if (g == 0) {
        Hw = lds_v0[f2];                      // virtual carry: y_{-1} = c0
    } else {
        Hw = {0.f, 0.f};
        #pragma unroll
        for (int j = 0; j < kSEG; ++j) {
            vf2 w = lds_w[j][f2];
            Hw.x = fmaf(kA4, Hw.x, w.x);
            Hw.y = fmaf(kA4, Hw.y, w.y);
        }
    }

    // ---- tile-0 carry-ins (capture own) + exact register carry I1 ----
    vf2 acc = Hw, yin0 = {0.f, 0.f};
    #pragma unroll
    for (int j = 0; j < kSEG; ++j) {
        if (j == seg) yin0 = acc;
        vf2 c = lds_c[0][j][f2];
        acc.x = fmaf(kA16, acc.x, c.x);
        acc.y = fmaf(kA16, acc.y, c.y);
    }
    const vf2 I1 = acc;

    // ---- fixup + store tile 0 ----
    vf2* op0 = out + rowbase + (size_t)(tg0 + seg * kL) * kF2;
    float ap = kA;
    #pragma unroll
    for (int j = 0; j < kL; ++j) {
        vf2 o;
        o.x = fmaxf(fmaf(ap, yin0.x, r[j].x), 0.f);
        o.y = fmaxf(fmaf(ap, yin0.y, r[j].y), 0.f);
        __builtin_nontemporal_store(o, op0 + (size_t)j * kF2);
        ap *= kA;
    }

    // ---- tile 1 local scan ----
    y = {0.f, 0.f};
    #pragma unroll
    for (int j = 0; j < kL; ++j) {
        vf2 v = comp(xv1[j]);
        y.x = fmaf(kA, y.x, kOmA * v.x);
        y.y = fmaf(kA, y.y, kOmA * v.y);
        r[j] = y;
    }
    lds_c[1][seg][f2] = y;
    __syncthreads();

    // ---- tile-1 carry-ins from I1 (exact, in-register) ----
    vf2 acc1 = I1, yin1 = {0.f, 0.f};
    #pragma unroll
    for (int j = 0; j < kSEG; ++j) {
        if (j == seg) yin1 = acc1;
        vf2 c = lds_c[1][j][f2];
        acc1.x = fmaf(kA16, acc1.x, c.x);
        acc1.y = fmaf(kA16, acc1.y, c.y);
    }

    // ---- fixup + store tile 1 ----
    vf2* op1 = op0 + (size_t)kTBLK * kF2;
    ap = kA;
    #pragma unroll
    for (int j = 0; j < kL; ++j) {
        vf2 o;
        o.x = fmaxf(fmaf(ap, yin1.x, r[j].x), 0.f);
        o.y = fmaxf(fmaf(ap, yin1.y, r[j].y), 0.f);
        __builtin_nontemporal_store(o, op1 + (size_t)j * kF2);
        ap *= kA;
    }
}

extern "C" void kernel_launch(void* const* d_in, const int* in_sizes, int n_in,
                              void* d_out, int out_size, void* d_ws, size_t ws_size,
                              hipStream_t stream) {
    const vf2*   spec  = (const vf2*)d_in[0];
    const vf2*   ftune = (const vf2*)d_in[1];
    const float* thr   = (const float*)d_in[2];
    const float* ratio = (const float*)d_in[3];
    vf2* out = (vf2*)d_out;

    dim3 grid(kB * kNG * 2), block(kSEG * kFH);   // 512 blocks x 256 threads
    cochlea_kernel<<<grid, block, 0, stream>>>(spec, ftune, thr, ratio, out);
}